// Round 5
// baseline (6184.978 us; speedup 1.0000x reference)
//
#include <hip/hip_runtime.h>
#include <hip/hip_fp16.h>

#define DEVINL __device__ __forceinline__

constexpr int B = 256, S = 512;
constexpr int H0 = 64, H1 = 128, H2 = 256;

typedef _Float16 f16x8 __attribute__((ext_vector_type(8)));
typedef float f32x4 __attribute__((ext_vector_type(4)));
typedef _Float16 h2v __attribute__((ext_vector_type(2)));

DEVINL float fexp2(float x) { return __builtin_amdgcn_exp2f(x); }
DEVINL float frcp(float x) { return __builtin_amdgcn_rcpf(x); }
DEVINL float fsig(float x) { return frcp(1.f + fexp2(-1.44269504088896f * x)); }
DEVINL float ftanh_(float x) { return 1.f - 2.f * frcp(1.f + fexp2(2.88539008177793f * x)); }
DEVINL h2v as_h2(unsigned u) { union { unsigned u; h2v h; } x; x.u = u; return x.h; }
DEVINL float fdot2(unsigned a, unsigned b, float c) {
  return __builtin_amdgcn_fdot2(as_h2(a), as_h2(b), c, false);
}
union FU { uint4 u; f16x8 h; };
DEVINL f16x8 as_f16x8(uint4 u) { FU x; x.u = u; return x.h; }

// LDS-only workgroup barrier: does NOT drain vmcnt, so global prefetches/stores
// stay in flight across the per-step barrier (unlike __syncthreads).
DEVINL void wg_barrier() {
  asm volatile("s_waitcnt lgkmcnt(0)" ::: "memory");
  __builtin_amdgcn_s_barrier();
  asm volatile("" ::: "memory");
}

// Row permutation: r' = mt*16 + quad*4 + reg -> channel = r'>>2, gate = r'&3.
// orig torch row = gate*Hch + channel. One C-frag lane holds one channel's
// (i,f,g,o) quad (C: col=lane&15, row=(lane>>4)*4+reg).

__global__ __launch_bounds__(256) void pack_frag(const float* __restrict__ w,
    uint4* __restrict__ wp, int Hch, int Kdim, int MT, int KT) {
  int o = blockIdx.x * 256 + threadIdx.x;
  if (o >= MT * KT * 64) return;
  int lane = o & 63, fk = o >> 6;
  int kt = fk % KT, mt = fk / KT;
  int rp = mt * 16 + (lane & 15);
  int orig = (rp & 3) * Hch + (rp >> 2);
  int k0 = kt * 32 + (lane >> 4) * 8;
  unsigned r[4];
#pragma unroll
  for (int p = 0; p < 4; ++p) {
    unsigned lo = __half_as_ushort(__float2half_rn(w[(size_t)orig * Kdim + k0 + 2 * p]));
    unsigned hi = __half_as_ushort(__float2half_rn(w[(size_t)orig * Kdim + k0 + 2 * p + 1]));
    r[p] = lo | (hi << 16);
  }
  uint4 v; v.x = r[0]; v.y = r[1]; v.z = r[2]; v.w = r[3];
  wp[o] = v;
}

__global__ __launch_bounds__(256) void pack_bias(const float* __restrict__ bih,
    const float* __restrict__ bhh, float* __restrict__ bs, int Hch) {
  int rp = blockIdx.x * 256 + threadIdx.x;
  if (rp >= 4 * Hch) return;
  int orig = (rp & 3) * Hch + (rp >> 2);
  bs[rp] = bih[orig] + bhh[orig];
}

__global__ void pack_wl(const float* __restrict__ wl, unsigned* __restrict__ wlp, int n) {
  int i = threadIdx.x;
  if (i < n) {
    unsigned lo = __half_as_ushort(__float2half_rn(wl[2 * i]));
    unsigned hi = __half_as_ushort(__float2half_rn(wl[2 * i + 1]));
    wlp[i] = lo | (hi << 16);
  }
}

__global__ __launch_bounds__(256) void f2h(const float* __restrict__ x,
                                           __half* __restrict__ y, int n8) {
  int i = blockIdx.x * 256 + threadIdx.x;
  if (i >= n8) return;
  float4 a = *(const float4*)(x + i * 8);
  float4 b = *(const float4*)(x + i * 8 + 4);
  __half h[8];
  h[0] = __float2half_rn(a.x); h[1] = __float2half_rn(a.y);
  h[2] = __float2half_rn(a.z); h[3] = __float2half_rn(a.w);
  h[4] = __float2half_rn(b.x); h[5] = __float2half_rn(b.y);
  h[6] = __float2half_rn(b.z); h[7] = __float2half_rn(b.w);
  *(uint4*)(y + i * 8) = *(const uint4*)h;
}

// MFMA input GEMM -> preT in C-frag layout.
template <int KT>
__global__ __launch_bounds__(256) void ingemm_mfma(const __half* __restrict__ x,
    const uint4* __restrict__ wp, const float* __restrict__ bs,
    f32x4* __restrict__ preT, int MT, int Sc, int t0) {
  constexpr int K = KT * 32;
  const int tid = threadIdx.x, w = tid >> 6, lane = tid & 63;
  const int n16 = lane & 15, quad = lane >> 4;
  const int bt = blockIdx.x, b0 = bt * 16;
  const int tlb = blockIdx.y * 8;
  const int mb = blockIdx.z * 16;

  uint4 areg[4][KT];
#pragma unroll
  for (int im = 0; im < 4; ++im)
#pragma unroll
    for (int kt = 0; kt < KT; ++kt)
      areg[im][kt] = wp[((size_t)(mb + w * 4 + im) * KT + kt) * 64 + lane];
  f32x4 bini[4];
#pragma unroll
  for (int im = 0; im < 4; ++im)
    bini[im] = *(const f32x4*)(bs + (mb + w * 4 + im) * 16 + quad * 4);

  for (int tt = 0; tt < 8; ++tt) {
    int t = t0 + tlb + tt;
    const __half* xr = x + ((size_t)(b0 + n16) * S + t) * K + quad * 8;
    uint4 bfr[KT];
#pragma unroll
    for (int kt = 0; kt < KT; ++kt) bfr[kt] = *(const uint4*)(xr + kt * 32);
    f32x4 acc[4];
#pragma unroll
    for (int im = 0; im < 4; ++im) acc[im] = bini[im];
#pragma unroll
    for (int kt = 0; kt < KT; ++kt)
#pragma unroll
      for (int im = 0; im < 4; ++im)
        acc[im] = __builtin_amdgcn_mfma_f32_16x16x32_f16(as_f16x8(areg[im][kt]),
                                                         as_f16x8(bfr[kt]), acc[im], 0, 0, 0);
#pragma unroll
    for (int im = 0; im < 4; ++im)
      preT[((size_t)(bt * Sc + tlb + tt) * MT + mb + w * 4 + im) * 64 + lane] = acc[im];
  }
}

// Weight-stationary recurrent scan; weights fully register-resident
// (launch_bounds(512,2) -> 256-VGPR cap). One LDS-only barrier per step
// (parity double-buffered h). SPLIT=2: m-dim split across WG pairs
// (blk, blk+16 -> same %8 -> same-XCD heuristic); peer h loaded per-lane
// directly from global after acquire-poll; own h exported by wave 0 only.
template <int H, int SPLIT, bool FINAL>
__global__ __launch_bounds__(512, 2) void scan_mfma(
    const uint4* __restrict__ wp, const f32x4* __restrict__ preT,
    __half* __restrict__ xout, float* __restrict__ out,
    const unsigned* __restrict__ wlp, const float* __restrict__ blp,
    float* __restrict__ sth, float* __restrict__ stc,
    unsigned* __restrict__ xh, int* __restrict__ flags,
    int Sc, int t0, int first) {
  constexpr int MT = H / 4;
  constexpr int MTO = MT / SPLIT;
  constexpr int MTW = MTO / 8;
  constexpr int KT = H / 32;
  constexpr int KTO = KT / SPLIT;
  constexpr int HO = H / SPLIT;      // own channels
  constexpr int HOP = HO + 8;        // padded row (halves); row stride 16B-aligned
  constexpr int HOD = HO / 2;        // own row in dwords

  __shared__ __half hbo[2][16 * HOP];
  __shared__ unsigned wls[FINAL ? H / 2 : 1];

  const int tid = threadIdx.x, w = tid >> 6, lane = tid & 63;
  const int n16 = lane & 15, quad = lane >> 4;
  int bt, half;
  if constexpr (SPLIT == 2) { bt = blockIdx.x & 15; half = blockIdx.x >> 4; }
  else { bt = blockIdx.x; half = 0; }
  const int phalf = 1 - half;
  const int b0 = bt * 16;
  const int mbase = half * MTO;

  uint4 areg[MTW][KT];
#pragma unroll
  for (int im = 0; im < MTW; ++im)
#pragma unroll
    for (int kt = 0; kt < KT; ++kt)
      areg[im][kt] = wp[((size_t)(mbase + w * MTW + im) * KT + kt) * 64 + lane];

  if constexpr (FINAL)
    for (int i = tid; i < H / 2; i += 512) wls[i] = wlp[i];

  float cst[MTW];
#pragma unroll
  for (int im = 0; im < MTW; ++im) {
    int ch = (mbase + w * MTW + im) * 4 + quad;
    cst[im] = first ? 0.f : stc[(size_t)(b0 + n16) * H + ch];
  }
  {
    int pi = (t0 - 1) & 1;
    for (int i = tid; i < 16 * HO; i += 512) {
      int n = i / HO, c = i % HO;
      hbo[pi][n * HOP + c] =
          first ? __float2half_rn(0.f)
                : __float2half_rn(sth[(size_t)(b0 + n) * H + half * HO + c]);
    }
  }
  __syncthreads();

  const float bl0 = FINAL ? blp[0] : 0.f;

  f32x4 nxt[MTW];
#pragma unroll
  for (int im = 0; im < MTW; ++im)
    nxt[im] = preT[((size_t)(bt * Sc) * MT + mbase + w * MTW + im) * 64 + lane];

  for (int tl = 0; tl < Sc; ++tl) {
    const int s = t0 + tl;
    const int pw = s & 1, pbl = pw ^ 1;
    f32x4 acc[MTW];
#pragma unroll
    for (int im = 0; im < MTW; ++im) acc[im] = nxt[im];
    if (tl + 1 < Sc) {
#pragma unroll
      for (int im = 0; im < MTW; ++im)
        nxt[im] = preT[((size_t)(bt * Sc + tl + 1) * MT + mbase + w * MTW + im) * 64 + lane];
    }

    // own-half B-frags (LDS) + MFMA
    uint4 bown[KTO];
#pragma unroll
    for (int ktl = 0; ktl < KTO; ++ktl)
      bown[ktl] = *(const uint4*)&hbo[pbl][n16 * HOP + ktl * 32 + quad * 8];
#pragma unroll
    for (int ktl = 0; ktl < KTO; ++ktl)
#pragma unroll
      for (int im = 0; im < MTW; ++im)
        acc[im] = __builtin_amdgcn_mfma_f32_16x16x32_f16(
            as_f16x8(areg[im][half * KTO + ktl]), as_f16x8(bown[ktl]), acc[im], 0, 0, 0);

    // peer-half B-frags (global, acquire-polled) + MFMA
    uint4 bpeer[(SPLIT == 2) ? KTO : 1];
    if constexpr (SPLIT == 2) {
      if (tl == 0) {
        if (first) {
#pragma unroll
          for (int ktl = 0; ktl < KTO; ++ktl)
            bpeer[ktl] = make_uint4(0, 0, 0, 0);
        } else {
#pragma unroll
          for (int ktl = 0; ktl < KTO; ++ktl) {
            const float* sp = sth + (size_t)(b0 + n16) * H + phalf * HO + ktl * 32 + quad * 8;
            float4 f0 = *(const float4*)sp, f1 = *(const float4*)(sp + 4);
            __half hx[8];
            hx[0] = __float2half_rn(f0.x); hx[1] = __float2half_rn(f0.y);
            hx[2] = __float2half_rn(f0.z); hx[3] = __float2half_rn(f0.w);
            hx[4] = __float2half_rn(f1.x); hx[5] = __float2half_rn(f1.y);
            hx[6] = __float2half_rn(f1.z); hx[7] = __float2half_rn(f1.w);
            bpeer[ktl] = *(const uint4*)hx;
          }
        }
      } else {
        while (__hip_atomic_load(&flags[bt * 2 + phalf], __ATOMIC_ACQUIRE,
                                 __HIP_MEMORY_SCOPE_AGENT) < s - 1)
          __builtin_amdgcn_s_sleep(1);
        const unsigned* src =
            xh + (((size_t)pbl * 16 + bt) * 2 + phalf) * (16 * HOD) + n16 * HOD;
#pragma unroll
        for (int ktl = 0; ktl < KTO; ++ktl)
          bpeer[ktl] = *(const uint4*)(src + ktl * 16 + quad * 4);
      }
#pragma unroll
      for (int ktl = 0; ktl < KTO; ++ktl)
#pragma unroll
        for (int im = 0; im < MTW; ++im)
          acc[im] = __builtin_amdgcn_mfma_f32_16x16x32_f16(
              as_f16x8(areg[im][phalf * KTO + ktl]), as_f16x8(bpeer[ktl]), acc[im], 0, 0, 0);
    }

    // outputs for step s-1 (h(s-1) = hbo[pbl] / bown+bpeer)
    if constexpr (!FINAL) {
      if (tl > 0 && tid < 16 * (H / 8)) {
        int n = tid / (H / 8), kq = tid % (H / 8);
        uint4 v = *(const uint4*)&hbo[pbl][n * HOP + kq * 8];
        *(uint4*)(xout + ((size_t)(b0 + n) * S + (s - 1)) * H + kq * 8) = v;
      }
    } else {
      if (half == 0 && w == 1 && tl > 0) {
        float sd = 0.f;
#pragma unroll
        for (int ktl = 0; ktl < KTO; ++ktl) {
          const unsigned* od = (const unsigned*)&bown[ktl];
          const unsigned* pd = (const unsigned*)&bpeer[ktl];
#pragma unroll
          for (int p = 0; p < 4; ++p) {
            sd = fdot2(od[p], wls[ktl * 16 + quad * 4 + p], sd);
            sd = fdot2(pd[p], wls[64 + ktl * 16 + quad * 4 + p], sd);
          }
        }
        sd += __shfl_xor(sd, 16); sd += __shfl_xor(sd, 32);
        if (lane < 16) out[(size_t)(b0 + lane) * S + (s - 1)] = ftanh_(sd + bl0);
      }
    }

    // gates (lane: one channel's i,f,g,o per m-tile)
    __half hh[MTW];
#pragma unroll
    for (int im = 0; im < MTW; ++im) {
      float gi = fsig(acc[im][0]);
      float gf = fsig(acc[im][1]);
      float gg = ftanh_(acc[im][2]);
      float go = fsig(acc[im][3]);
      float cn = gf * cst[im] + gi * gg;
      cst[im] = cn;
      hh[im] = __float2half_rn(go * ftanh_(cn));
    }
#pragma unroll
    for (int im = 0; im < MTW; ++im)
      hbo[pw][n16 * HOP + (w * MTW + im) * 4 + quad] = hh[im];

    wg_barrier();  // LDS-only: global ops stay in flight

    if constexpr (SPLIT == 2) {
      // wave 0 exports own half + release flag; waves 1-7 run ahead
      if (w == 0) {
        unsigned* dst = xh + (((size_t)pw * 16 + bt) * 2 + half) * (16 * HOD);
#pragma unroll
        for (int j = 0; j < 16 * HOD / 64; ++j) {
          int d = j * 64 + lane;
          int n = d / HOD, c2 = d % HOD;
          unsigned v = *(const unsigned*)&hbo[pw][n * HOP + c2 * 2];
          __hip_atomic_store(dst + d, v, __ATOMIC_RELAXED, __HIP_MEMORY_SCOPE_AGENT);
        }
        if (lane == 0)
          __hip_atomic_store(&flags[bt * 2 + half], s, __ATOMIC_RELEASE,
                             __HIP_MEMORY_SCOPE_AGENT);
      }
    }
  }

  // tail outputs for the chunk's last step
  {
    const int sl = t0 + Sc - 1;
    const int pl = sl & 1;
    if constexpr (!FINAL) {
      if (tid < 16 * (H / 8)) {
        int n = tid / (H / 8), kq = tid % (H / 8);
        uint4 v = *(const uint4*)&hbo[pl][n * HOP + kq * 8];
        *(uint4*)(xout + ((size_t)(b0 + n) * S + sl) * H + kq * 8) = v;
      }
    } else {
      if (half == 0 && w == 1) {
        while (__hip_atomic_load(&flags[bt * 2 + phalf], __ATOMIC_ACQUIRE,
                                 __HIP_MEMORY_SCOPE_AGENT) < sl)
          __builtin_amdgcn_s_sleep(1);
        const unsigned* src =
            xh + (((size_t)pl * 16 + bt) * 2 + phalf) * (16 * HOD) + n16 * HOD;
        float sd = 0.f;
#pragma unroll
        for (int ktl = 0; ktl < KTO; ++ktl) {
          uint4 bo = *(const uint4*)&hbo[pl][n16 * HOP + ktl * 32 + quad * 8];
          uint4 bp = *(const uint4*)(src + ktl * 16 + quad * 4);
          const unsigned* od = (const unsigned*)&bo;
          const unsigned* pd = (const unsigned*)&bp;
#pragma unroll
          for (int p = 0; p < 4; ++p) {
            sd = fdot2(od[p], wls[ktl * 16 + quad * 4 + p], sd);
            sd = fdot2(pd[p], wls[64 + ktl * 16 + quad * 4 + p], sd);
          }
        }
        sd += __shfl_xor(sd, 16); sd += __shfl_xor(sd, 32);
        if (lane < 16) out[(size_t)(b0 + lane) * S + sl] = ftanh_(sd + bl0);
      }
    }
    // state carry (own half only)
    for (int i = tid; i < 16 * HO; i += 512) {
      int n = i / HO, c = i % HO;
      sth[(size_t)(b0 + n) * H + half * HO + c] = __half2float(hbo[pl][n * HOP + c]);
    }
#pragma unroll
    for (int im = 0; im < MTW; ++im) {
      int ch = (mbase + w * MTW + im) * 4 + quad;
      stc[(size_t)(b0 + n16) * H + ch] = cst[im];
    }
  }
}

extern "C" void kernel_launch(void* const* d_in, const int* in_sizes, int n_in,
                              void* d_out, int out_size, void* d_ws, size_t ws_size,
                              hipStream_t stream) {
  (void)in_sizes; (void)n_in; (void)out_size;
  const float* noise = (const float*)d_in[0];
  const float* Wih0 = (const float*)d_in[1];
  const float* Whh0 = (const float*)d_in[2];
  const float* bih0 = (const float*)d_in[3];
  const float* bhh0 = (const float*)d_in[4];
  const float* Wih1 = (const float*)d_in[5];
  const float* Whh1 = (const float*)d_in[6];
  const float* bih1 = (const float*)d_in[7];
  const float* bhh1 = (const float*)d_in[8];
  const float* Wih2 = (const float*)d_in[9];
  const float* Whh2 = (const float*)d_in[10];
  const float* bih2 = (const float*)d_in[11];
  const float* bhh2 = (const float*)d_in[12];
  const float* Wl = (const float*)d_in[13];
  const float* bl = (const float*)d_in[14];
  float* out = (float*)d_out;

  char* p = (char*)d_ws;
  auto alloc = [&](size_t bytes) {
    char* r = p;
    p += (bytes + 255) & ~(size_t)255;
    return r;
  };
  uint4* wpH0 = (uint4*)alloc((size_t)16 * 2 * 1024);
  uint4* wpH1 = (uint4*)alloc((size_t)32 * 4 * 1024);
  uint4* wpH2 = (uint4*)alloc((size_t)64 * 8 * 1024);
  uint4* wpI0 = (uint4*)alloc((size_t)16 * 1 * 1024);
  uint4* wpI1 = (uint4*)alloc((size_t)32 * 2 * 1024);
  uint4* wpI2 = (uint4*)alloc((size_t)64 * 4 * 1024);
  float* bs0 = (float*)alloc(256 * 4);
  float* bs1 = (float*)alloc(512 * 4);
  float* bs2 = (float*)alloc(1024 * 4);
  unsigned* wlp = (unsigned*)alloc(128 * 4);
  float* sh0 = (float*)alloc((size_t)B * H0 * 4);
  float* sc0 = (float*)alloc((size_t)B * H0 * 4);
  float* sh1 = (float*)alloc((size_t)B * H1 * 4);
  float* sc1 = (float*)alloc((size_t)B * H1 * 4);
  float* sh2 = (float*)alloc((size_t)B * H2 * 4);
  float* sc2 = (float*)alloc((size_t)B * H2 * 4);
  __half* x0 = (__half*)alloc((size_t)B * S * 32 * 2);
  __half* x1 = (__half*)alloc((size_t)B * S * H0 * 2);
  __half* x2 = (__half*)alloc((size_t)B * S * H1 * 2);
  unsigned* xh = (unsigned*)alloc((size_t)2 * 16 * 2 * 1024 * 4);
  int* flags = (int*)alloc(64 * 4);
  size_t fixed = (size_t)(p - (char*)d_ws);
  int Sc = 128;
  while (Sc > 16 && fixed + (size_t)B * Sc * 1024 * 4 > ws_size) Sc >>= 1;
  float* preT = (float*)alloc((size_t)B * Sc * 1024 * 4);

  pack_frag<<<(16 * 2 * 64 + 255) / 256, 256, 0, stream>>>(Whh0, wpH0, 64, 64, 16, 2);
  pack_frag<<<(32 * 4 * 64 + 255) / 256, 256, 0, stream>>>(Whh1, wpH1, 128, 128, 32, 4);
  pack_frag<<<(64 * 8 * 64 + 255) / 256, 256, 0, stream>>>(Whh2, wpH2, 256, 256, 64, 8);
  pack_frag<<<(16 * 1 * 64 + 255) / 256, 256, 0, stream>>>(Wih0, wpI0, 64, 32, 16, 1);
  pack_frag<<<(32 * 2 * 64 + 255) / 256, 256, 0, stream>>>(Wih1, wpI1, 128, 64, 32, 2);
  pack_frag<<<(64 * 4 * 64 + 255) / 256, 256, 0, stream>>>(Wih2, wpI2, 256, 128, 64, 4);
  pack_bias<<<1, 256, 0, stream>>>(bih0, bhh0, bs0, 64);
  pack_bias<<<2, 256, 0, stream>>>(bih1, bhh1, bs1, 128);
  pack_bias<<<4, 256, 0, stream>>>(bih2, bhh2, bs2, 256);
  pack_wl<<<1, 128, 0, stream>>>(Wl, wlp, 128);
  f2h<<<(B * S * 32 / 8 + 255) / 256, 256, 0, stream>>>(noise, x0, B * S * 32 / 8);

  for (int c = 0; c < S / Sc; ++c) {
    int t0 = c * Sc;
    ingemm_mfma<1><<<dim3(16, Sc / 8, 1), 256, 0, stream>>>(x0, wpI0, bs0,
                                                            (f32x4*)preT, 16, Sc, t0);
    scan_mfma<64, 1, false><<<16, 512, 0, stream>>>(
        wpH0, (const f32x4*)preT, x1, nullptr, nullptr, nullptr, sh0, sc0,
        nullptr, nullptr, Sc, t0, c == 0);
    ingemm_mfma<2><<<dim3(16, Sc / 8, 2), 256, 0, stream>>>(x1, wpI1, bs1,
                                                            (f32x4*)preT, 32, Sc, t0);
    scan_mfma<128, 1, false><<<16, 512, 0, stream>>>(
        wpH1, (const f32x4*)preT, x2, nullptr, nullptr, nullptr, sh1, sc1,
        nullptr, nullptr, Sc, t0, c == 0);
    ingemm_mfma<4><<<dim3(16, Sc / 8, 4), 256, 0, stream>>>(x2, wpI2, bs2,
                                                            (f32x4*)preT, 64, Sc, t0);
    scan_mfma<256, 2, true><<<32, 512, 0, stream>>>(
        wpH2, (const f32x4*)preT, nullptr, out, wlp, bl, sh2, sc2,
        xh, flags, Sc, t0, c == 0);
  }
}